// Round 3
// baseline (285.413 us; speedup 1.0000x reference)
//
#include <hip/hip_runtime.h>

#define DOUT 256          // embedding dim
#define NROWS 49152       // 64 king squares * 12 planes * 64 squares
#define MAT_BLOCKS (NROWS / 4)

__device__ __forceinline__ float4 ld4(const float* p) {
  return *reinterpret_cast<const float4*>(p);
}
__device__ __forceinline__ void acc4(float4& a, const float4 b) {
  a.x += b.x; a.y += b.y; a.z += b.z; a.w += b.w;
}

// ---- materialize merged = tiles + (pieces+ranks+files)*mask; last block
// ---- also does the exclusive prefix scan of lengths -> offs (independent).
__global__ __launch_bounds__(256) void mat_scan_kernel(
    const float* __restrict__ tiles, const float* __restrict__ pieces,
    const float* __restrict__ ranks, const float* __restrict__ files,
    const float* __restrict__ mask, float* __restrict__ merged,
    const int* __restrict__ lengths, int* __restrict__ offs, int n_bags) {
  if (blockIdx.x == MAT_BLOCKS) {
    // ---- scan block: 256 threads, contiguous chunks ----
    __shared__ int part[256];
    const int t = threadIdx.x;
    const int chunk = (n_bags + 255) / 256;
    const int base = t * chunk;
    int s = 0;
    for (int j = 0; j < chunk; ++j) {
      int idx = base + j;
      if (idx < n_bags) s += lengths[idx];
    }
    part[t] = s;
    __syncthreads();
    for (int off = 1; off < 256; off <<= 1) {
      int v = (t >= off) ? part[t - off] : 0;
      __syncthreads();
      part[t] += v;
      __syncthreads();
    }
    int run = part[t] - s;  // exclusive base of this thread's chunk
    for (int j = 0; j < chunk; ++j) {
      int idx = base + j;
      if (idx < n_bags) { offs[idx] = run; run += lengths[idx]; }
    }
    return;
  }
  const int row = (blockIdx.x << 2) + (threadIdx.x >> 6);  // 0..NROWS-1
  const int lane = threadIdx.x & 63;
  const int p = row & 63;       // square within plane: r*8+f
  const int sk = row >> 6;      // s*12 + k
  const int r = p >> 3, f = p & 7;
  const float m = mask[row];
  const int d0 = lane << 2;
  float4 t = ld4(tiles + (size_t)row * DOUT + d0);
  float4 pc = ld4(pieces + (size_t)sk * DOUT + d0);
  float4 rk = ld4(ranks + ((size_t)(sk * 8 + r)) * DOUT + d0);
  float4 fl = ld4(files + ((size_t)(sk * 8 + f)) * DOUT + d0);
  float4 o;
  o.x = fmaf(pc.x + rk.x + fl.x, m, t.x);
  o.y = fmaf(pc.y + rk.y + fl.y, m, t.y);
  o.z = fmaf(pc.z + rk.z + fl.z, m, t.z);
  o.w = fmaf(pc.w + rk.w + fl.w, m, t.w);
  *reinterpret_cast<float4*>(merged + (size_t)row * DOUT + d0) = o;
}

// ---------------- gather: one wave per bag, 4x unrolled ----------------
// rowA(v) = km*768 + (k<<6) + p
// rowB(v) = sw*768 + (k2<<6) + (p^56), k2 = (k+6)%12, p^56 flips the rank
__global__ __launch_bounds__(256) void gather_kernel(
    const float* __restrict__ merged,
    const int* __restrict__ values, const int* __restrict__ lengths,
    const int* __restrict__ kings, const int* __restrict__ offs,
    float* __restrict__ out, int n_bags) {
  const int bag = (blockIdx.x << 2) + (threadIdx.x >> 6);
  const int lane = threadIdx.x & 63;
  if (bag >= n_bags) return;
  const int len = lengths[bag];
  const int km = kings[2 * bag];
  const int kw = kings[2 * bag + 1];
  const int km768 = km * 768;
  const int sw768 = (((7 - (kw >> 3)) << 3) + (kw & 7)) * 768;  // flipped sq
  const int* __restrict__ vals = values + offs[bag];
  const float* __restrict__ mb = merged + (lane << 2);  // bake d0 into base

  float4 aA0 = {0.f,0.f,0.f,0.f}, aA1 = {0.f,0.f,0.f,0.f};
  float4 aB0 = {0.f,0.f,0.f,0.f}, aB1 = {0.f,0.f,0.f,0.f};

  int i = 0;
  for (; i + 4 <= len; i += 4) {
    const int v0 = vals[i], v1 = vals[i + 1], v2 = vals[i + 2], v3 = vals[i + 3];
    const int k0 = v0 >> 6, p0 = v0 & 63;
    const int k1 = v1 >> 6, p1 = v1 & 63;
    const int k2_ = v2 >> 6, p2 = v2 & 63;
    const int k3 = v3 >> 6, p3 = v3 & 63;
    const unsigned rA0 = km768 + (k0 << 6) + p0;
    const unsigned rA1 = km768 + (k1 << 6) + p1;
    const unsigned rA2 = km768 + (k2_ << 6) + p2;
    const unsigned rA3 = km768 + (k3 << 6) + p3;
    const unsigned rB0 = sw768 + (((k0 < 6) ? k0 + 6 : k0 - 6) << 6) + (p0 ^ 56);
    const unsigned rB1 = sw768 + (((k1 < 6) ? k1 + 6 : k1 - 6) << 6) + (p1 ^ 56);
    const unsigned rB2 = sw768 + (((k2_ < 6) ? k2_ + 6 : k2_ - 6) << 6) + (p2 ^ 56);
    const unsigned rB3 = sw768 + (((k3 < 6) ? k3 + 6 : k3 - 6) << 6) + (p3 ^ 56);
    // issue all 8 loads before any use -> 8 in-flight dwordx4 per wave
    const float4 a0 = ld4(mb + ((size_t)rA0 << 8));
    const float4 b0 = ld4(mb + ((size_t)rB0 << 8));
    const float4 a1 = ld4(mb + ((size_t)rA1 << 8));
    const float4 b1 = ld4(mb + ((size_t)rB1 << 8));
    const float4 a2 = ld4(mb + ((size_t)rA2 << 8));
    const float4 b2 = ld4(mb + ((size_t)rB2 << 8));
    const float4 a3 = ld4(mb + ((size_t)rA3 << 8));
    const float4 b3 = ld4(mb + ((size_t)rB3 << 8));
    acc4(aA0, a0); acc4(aA1, a1); acc4(aA0, a2); acc4(aA1, a3);
    acc4(aB0, b0); acc4(aB1, b1); acc4(aB0, b2); acc4(aB1, b3);
  }
  for (; i < len; ++i) {
    const int v = vals[i];
    const int k = v >> 6, p = v & 63;
    const unsigned rA = km768 + (k << 6) + p;
    const unsigned rB = sw768 + (((k < 6) ? k + 6 : k - 6) << 6) + (p ^ 56);
    acc4(aA0, ld4(mb + ((size_t)rA << 8)));
    acc4(aB0, ld4(mb + ((size_t)rB << 8)));
  }

  float4 oa, ob;
  oa.x = fminf(fmaxf(aA0.x + aA1.x, 0.f), 1.f);
  oa.y = fminf(fmaxf(aA0.y + aA1.y, 0.f), 1.f);
  oa.z = fminf(fmaxf(aA0.z + aA1.z, 0.f), 1.f);
  oa.w = fminf(fmaxf(aA0.w + aA1.w, 0.f), 1.f);
  ob.x = fminf(fmaxf(aB0.x + aB1.x, 0.f), 1.f);
  ob.y = fminf(fmaxf(aB0.y + aB1.y, 0.f), 1.f);
  ob.z = fminf(fmaxf(aB0.z + aB1.z, 0.f), 1.f);
  ob.w = fminf(fmaxf(aB0.w + aB1.w, 0.f), 1.f);
  reinterpret_cast<float4*>(out)[(size_t)bag * 64 + lane] = oa;
  reinterpret_cast<float4*>(out)[(size_t)n_bags * 64 + (size_t)bag * 64 + lane] = ob;
}

extern "C" void kernel_launch(void* const* d_in, const int* in_sizes, int n_in,
                              void* d_out, int out_size, void* d_ws, size_t ws_size,
                              hipStream_t stream) {
  const float* pieces = (const float*)d_in[0];
  const float* ranks  = (const float*)d_in[1];
  const float* files  = (const float*)d_in[2];
  const float* tiles  = (const float*)d_in[3];
  const float* mask   = (const float*)d_in[4];
  const int*   values = (const int*)d_in[5];
  const int*   lengths= (const int*)d_in[6];
  const int*   kings  = (const int*)d_in[7];
  float* out = (float*)d_out;

  const int B = in_sizes[6];  // number of bags

  int* offs = (int*)d_ws;
  const size_t merged_off = 65536;  // bytes reserved for offs
  float* merged = (float*)((char*)d_ws + merged_off);

  mat_scan_kernel<<<MAT_BLOCKS + 1, 256, 0, stream>>>(
      tiles, pieces, ranks, files, mask, merged, lengths, offs, B);

  const int gather_blocks = (B + 3) / 4;
  gather_kernel<<<gather_blocks, 256, 0, stream>>>(
      merged, values, lengths, kings, offs, out, B);
}

// Round 4
// 206.460 us; speedup vs baseline: 1.3824x; 1.3824x over previous
//
#include <hip/hip_runtime.h>

#define DOUT 256
#define NROWS 49152          // 64 king squares * 12 planes * 64 squares
#define SKS 768              // 64*12 (s,k) planes
#define MAT_BLOCKS SKS       // one block per sk-plane; +1 scan, +2 sorts

__device__ __forceinline__ float4 ld4(const float* p) {
  return *reinterpret_cast<const float4*>(p);
}
__device__ __forceinline__ void acc4(float4& a, const float4 b) {
  a.x += b.x; a.y += b.y; a.z += b.z; a.w += b.w;
}

// prep: materialize merged (one block per sk-plane, factors in registers),
// plus 1 scan block (offs) and 2 counting-sort blocks (perm by king col).
__global__ __launch_bounds__(256) void prep_kernel(
    const float* __restrict__ tiles, const float* __restrict__ pieces,
    const float* __restrict__ ranks, const float* __restrict__ files,
    const float* __restrict__ mask, float* __restrict__ merged,
    const int* __restrict__ lengths, const int* __restrict__ kings,
    int* __restrict__ offs, int* __restrict__ perm_m, int* __restrict__ perm_w,
    int n_bags) {
  const int bid = blockIdx.x;
  const int t = threadIdx.x;
  if (bid < MAT_BLOCKS) {
    const int sk = bid;
    const float pc = pieces[sk * 256 + t];
    float rk[8], fl[8];
#pragma unroll
    for (int r = 0; r < 8; ++r) rk[r] = ranks[(size_t)(sk * 8 + r) * 256 + t];
#pragma unroll
    for (int f = 0; f < 8; ++f) fl[f] = files[(size_t)(sk * 8 + f) * 256 + t];
    const float* trow = tiles + (size_t)sk * 64 * 256;
    float* orow = merged + (size_t)sk * 64 * 256;
    const float* mrow = mask + sk * 64;
#pragma unroll 4
    for (int p = 0; p < 64; ++p) {
      const float m = mrow[p];
      orow[p * 256 + t] = fmaf(pc + rk[p >> 3] + fl[p & 7], m, trow[p * 256 + t]);
    }
    return;
  }
  if (bid == MAT_BLOCKS) {
    // exclusive prefix scan of lengths -> offs
    __shared__ int part[256];
    const int chunk = (n_bags + 255) / 256;
    const int base = t * chunk;
    int s = 0;
    for (int j = 0; j < chunk; ++j) {
      int idx = base + j;
      if (idx < n_bags) s += lengths[idx];
    }
    part[t] = s;
    __syncthreads();
    for (int off = 1; off < 256; off <<= 1) {
      int v = (t >= off) ? part[t - off] : 0;
      __syncthreads();
      part[t] += v;
      __syncthreads();
    }
    int run = part[t] - s;
    for (int j = 0; j < chunk; ++j) {
      int idx = base + j;
      if (idx < n_bags) { offs[idx] = run; run += lengths[idx]; }
    }
    return;
  }
  // counting sort of bag ids by king square (col 0 -> perm_m, col 1 -> perm_w)
  const int col = bid - (MAT_BLOCKS + 1);  // 0 or 1
  int* __restrict__ perm = col ? perm_w : perm_m;
  __shared__ int hist[64];
  if (t < 64) hist[t] = 0;
  __syncthreads();
  for (int i = t; i < n_bags; i += 256) {
    atomicAdd(&hist[kings[2 * i + col]], 1);
  }
  __syncthreads();
  __shared__ int start[64];
  if (t == 0) {
    int run = 0;
    for (int k = 0; k < 64; ++k) { start[k] = run; run += hist[k]; }
  }
  __syncthreads();
  if (t < 64) hist[t] = start[t];  // reuse as cursor
  __syncthreads();
  for (int i = t; i < n_bags; i += 256) {
    int pos = atomicAdd(&hist[kings[2 * i + col]], 1);
    perm[pos] = i;
  }
}

// gather: one wave per bag, bags sorted by king so each XCD (bid%8) walks
// a contiguous king range -> table slice stays L2-resident.
// First half of blocks: mover view (a). Second half: waiter/flipped view (b).
template <bool WAITER>
__device__ __forceinline__ void gather_body(
    const float* __restrict__ merged, const int* __restrict__ values,
    const int* __restrict__ lengths, const int* __restrict__ kings,
    const int* __restrict__ offs, const int* __restrict__ perm,
    float* __restrict__ out, int n_bags, int chunk, int b) {
  const int c = b & 7;          // XCD id under bid%8 round-robin
  const int j = b >> 3;         // sequence within this XCD's chunk
  const int pos = c * chunk + (j << 2) + (threadIdx.x >> 6);
  const int lim = min((c + 1) * chunk, n_bags);
  if (pos >= lim) return;
  const int lane = threadIdx.x & 63;
  const int bag = perm[pos];
  const int len = lengths[bag];
  const int kg = kings[2 * bag + (WAITER ? 1 : 0)];
  const int base = (WAITER ? (((7 - (kg >> 3)) << 3) + (kg & 7)) : kg) * 768;
  const int* __restrict__ vals = values + offs[bag];
  const float* __restrict__ mb = merged + (lane << 2);

  float4 a0 = {0.f, 0.f, 0.f, 0.f}, a1 = {0.f, 0.f, 0.f, 0.f};

  int i = 0;
  for (; i + 4 <= len; i += 4) {
    const int v0 = vals[i], v1 = vals[i + 1], v2 = vals[i + 2], v3 = vals[i + 3];
    unsigned r0, r1, r2, r3;
    if (WAITER) {
      const int k0 = v0 >> 6, k1 = v1 >> 6, k2 = v2 >> 6, k3 = v3 >> 6;
      r0 = base + ((k0 < 6 ? k0 + 6 : k0 - 6) << 6) + ((v0 & 63) ^ 56);
      r1 = base + ((k1 < 6 ? k1 + 6 : k1 - 6) << 6) + ((v1 & 63) ^ 56);
      r2 = base + ((k2 < 6 ? k2 + 6 : k2 - 6) << 6) + ((v2 & 63) ^ 56);
      r3 = base + ((k3 < 6 ? k3 + 6 : k3 - 6) << 6) + ((v3 & 63) ^ 56);
    } else {
      r0 = base + v0; r1 = base + v1; r2 = base + v2; r3 = base + v3;
    }
    const float4 x0 = ld4(mb + ((size_t)r0 << 8));
    const float4 x1 = ld4(mb + ((size_t)r1 << 8));
    const float4 x2 = ld4(mb + ((size_t)r2 << 8));
    const float4 x3 = ld4(mb + ((size_t)r3 << 8));
    acc4(a0, x0); acc4(a1, x1); acc4(a0, x2); acc4(a1, x3);
  }
  for (; i < len; ++i) {
    const int v = vals[i];
    unsigned r;
    if (WAITER) {
      const int k = v >> 6;
      r = base + ((k < 6 ? k + 6 : k - 6) << 6) + ((v & 63) ^ 56);
    } else {
      r = base + v;
    }
    acc4(a0, ld4(mb + ((size_t)r << 8)));
  }

  float4 o;
  o.x = fminf(fmaxf(a0.x + a1.x, 0.f), 1.f);
  o.y = fminf(fmaxf(a0.y + a1.y, 0.f), 1.f);
  o.z = fminf(fmaxf(a0.z + a1.z, 0.f), 1.f);
  o.w = fminf(fmaxf(a0.w + a1.w, 0.f), 1.f);
  float4* ob = reinterpret_cast<float4*>(out) +
               (WAITER ? (size_t)n_bags * 64 : 0);
  ob[(size_t)bag * 64 + lane] = o;
}

__global__ __launch_bounds__(256) void gather_kernel(
    const float* __restrict__ merged, const int* __restrict__ values,
    const int* __restrict__ lengths, const int* __restrict__ kings,
    const int* __restrict__ offs, const int* __restrict__ perm_m,
    const int* __restrict__ perm_w, float* __restrict__ out, int n_bags,
    int chunk, int half_blocks) {
  const int b = blockIdx.x;
  if (b < half_blocks) {
    gather_body<false>(merged, values, lengths, kings, offs, perm_m, out,
                       n_bags, chunk, b);
  } else {
    gather_body<true>(merged, values, lengths, kings, offs, perm_w, out,
                      n_bags, chunk, b - half_blocks);
  }
}

extern "C" void kernel_launch(void* const* d_in, const int* in_sizes, int n_in,
                              void* d_out, int out_size, void* d_ws, size_t ws_size,
                              hipStream_t stream) {
  const float* pieces = (const float*)d_in[0];
  const float* ranks  = (const float*)d_in[1];
  const float* files  = (const float*)d_in[2];
  const float* tiles  = (const float*)d_in[3];
  const float* mask   = (const float*)d_in[4];
  const int*   values = (const int*)d_in[5];
  const int*   lengths= (const int*)d_in[6];
  const int*   kings  = (const int*)d_in[7];
  float* out = (float*)d_out;

  const int B = in_sizes[6];  // number of bags

  // workspace layout (256B aligned)
  const size_t bN = ((size_t)B * 4 + 255) & ~(size_t)255;
  int* offs   = (int*)d_ws;
  int* perm_m = (int*)((char*)d_ws + bN);
  int* perm_w = (int*)((char*)d_ws + 2 * bN);
  float* merged = (float*)((char*)d_ws + 3 * bN);

  prep_kernel<<<MAT_BLOCKS + 3, 256, 0, stream>>>(
      tiles, pieces, ranks, files, mask, merged, lengths, kings,
      offs, perm_m, perm_w, B);

  const int chunk = (B + 7) / 8;                 // bags per XCD chunk
  const int half_blocks = 8 * ((chunk + 3) / 4); // blocks per view
  gather_kernel<<<2 * half_blocks, 256, 0, stream>>>(
      merged, values, lengths, kings, offs, perm_m, perm_w, out, B,
      chunk, half_blocks);
}

// Round 5
// 197.871 us; speedup vs baseline: 1.4424x; 1.0434x over previous
//
#include <hip/hip_runtime.h>

#define DOUT 256
#define NROWS 49152          // 64 king squares * 12 planes * 64 squares
#define MAT_BLOCKS (NROWS / 4)  // 4 rows per block

__device__ __forceinline__ float4 ld4(const float* p) {
  return *reinterpret_cast<const float4*>(p);
}

// round-to-nearest-even f32 -> bf16, packed pair (a in low16, b in high16)
__device__ __forceinline__ unsigned rne2(float a, float b) {
  unsigned ua = __float_as_uint(a), ub = __float_as_uint(b);
  ua += 0x7FFFu + ((ua >> 16) & 1u);
  ub += 0x7FFFu + ((ub >> 16) & 1u);
  return (ua >> 16) | (ub & 0xFFFF0000u);
}

// accumulate 4 bf16 (packed in uint2) into float4
__device__ __forceinline__ void bf4_acc(uint2 w, float4& acc) {
  acc.x += __uint_as_float(w.x << 16);
  acc.y += __uint_as_float(w.x & 0xFFFF0000u);
  acc.z += __uint_as_float(w.y << 16);
  acc.w += __uint_as_float(w.y & 0xFFFF0000u);
}

// prep: materialize merged table in bf16 (12288 blocks, float4 loads),
// +1 scan block (offs), +2 counting-sort blocks (perm by king column).
__global__ __launch_bounds__(256) void prep_kernel(
    const float* __restrict__ tiles, const float* __restrict__ pieces,
    const float* __restrict__ ranks, const float* __restrict__ files,
    const float* __restrict__ mask, uint2* __restrict__ merged,
    const int* __restrict__ lengths, const int* __restrict__ kings,
    int* __restrict__ offs, int* __restrict__ perm_m, int* __restrict__ perm_w,
    int n_bags) {
  const int bid = blockIdx.x;
  const int t = threadIdx.x;
  if (bid < MAT_BLOCKS) {
    const int row = (bid << 2) + (t >> 6);
    const int lane = t & 63;
    const int p = row & 63;
    const int sk = row >> 6;
    const int r = p >> 3, f = p & 7;
    const float m = mask[row];
    const int d0 = lane << 2;
    float4 tl = ld4(tiles + (size_t)row * DOUT + d0);
    float4 pc = ld4(pieces + (size_t)sk * DOUT + d0);
    float4 rk = ld4(ranks + (size_t)(sk * 8 + r) * DOUT + d0);
    float4 fl = ld4(files + (size_t)(sk * 8 + f) * DOUT + d0);
    float4 o;
    o.x = fmaf(pc.x + rk.x + fl.x, m, tl.x);
    o.y = fmaf(pc.y + rk.y + fl.y, m, tl.y);
    o.z = fmaf(pc.z + rk.z + fl.z, m, tl.z);
    o.w = fmaf(pc.w + rk.w + fl.w, m, tl.w);
    uint2 w;
    w.x = rne2(o.x, o.y);
    w.y = rne2(o.z, o.w);
    merged[(size_t)row * 64 + lane] = w;
    return;
  }
  if (bid == MAT_BLOCKS) {
    // exclusive prefix scan of lengths -> offs
    __shared__ int part[256];
    const int chunk = (n_bags + 255) / 256;
    const int base = t * chunk;
    int s = 0;
    for (int j = 0; j < chunk; ++j) {
      int idx = base + j;
      if (idx < n_bags) s += lengths[idx];
    }
    part[t] = s;
    __syncthreads();
    for (int off = 1; off < 256; off <<= 1) {
      int v = (t >= off) ? part[t - off] : 0;
      __syncthreads();
      part[t] += v;
      __syncthreads();
    }
    int run = part[t] - s;
    for (int j = 0; j < chunk; ++j) {
      int idx = base + j;
      if (idx < n_bags) { offs[idx] = run; run += lengths[idx]; }
    }
    return;
  }
  // counting sort of bag ids by king square (col 0 -> perm_m, col 1 -> perm_w)
  const int col = bid - (MAT_BLOCKS + 1);  // 0 or 1
  int* __restrict__ perm = col ? perm_w : perm_m;
  __shared__ int hist[64];
  __shared__ int start[64];
  if (t < 64) hist[t] = 0;
  __syncthreads();
  for (int i = t; i < n_bags; i += 256) {
    atomicAdd(&hist[kings[2 * i + col]], 1);
  }
  __syncthreads();
  if (t == 0) {
    int run = 0;
    for (int k = 0; k < 64; ++k) { start[k] = run; run += hist[k]; }
  }
  __syncthreads();
  if (t < 64) hist[t] = start[t];  // reuse as cursor
  __syncthreads();
  for (int i = t; i < n_bags; i += 256) {
    int pos = atomicAdd(&hist[kings[2 * i + col]], 1);
    perm[pos] = i;
  }
}

// gather: one wave per bag over the bf16 table; bags sorted by king so each
// XCD (bid%8) walks a contiguous king range -> slice (393 KB) L2-resident.
// First half of blocks: mover view (a). Second half: waiter/flipped view (b).
template <bool WAITER>
__device__ __forceinline__ void gather_body(
    const uint2* __restrict__ merged, const int* __restrict__ values,
    const int* __restrict__ lengths, const int* __restrict__ kings,
    const int* __restrict__ offs, const int* __restrict__ perm,
    float* __restrict__ out, int n_bags, int chunk, int b) {
  const int c = b & 7;          // XCD id under bid%8 round-robin
  const int j = b >> 3;         // sequence within this XCD's chunk
  const int pos = c * chunk + (j << 2) + (threadIdx.x >> 6);
  const int lim = min((c + 1) * chunk, n_bags);
  if (pos >= lim) return;
  const int lane = threadIdx.x & 63;
  const int bag = perm[pos];
  const int len = lengths[bag];
  const int kg = kings[2 * bag + (WAITER ? 1 : 0)];
  const int base = (WAITER ? (((7 - (kg >> 3)) << 3) + (kg & 7)) : kg) * 768;
  const int* __restrict__ vals = values + offs[bag];
  const uint2* __restrict__ mb = merged + lane;  // lane covers dims 4l..4l+3

  float4 a0 = {0.f, 0.f, 0.f, 0.f}, a1 = {0.f, 0.f, 0.f, 0.f};

  int i = 0;
  for (; i + 4 <= len; i += 4) {
    const int v0 = vals[i], v1 = vals[i + 1], v2 = vals[i + 2], v3 = vals[i + 3];
    unsigned r0, r1, r2, r3;
    if (WAITER) {
      const int k0 = v0 >> 6, k1 = v1 >> 6, k2 = v2 >> 6, k3 = v3 >> 6;
      r0 = base + ((k0 < 6 ? k0 + 6 : k0 - 6) << 6) + ((v0 & 63) ^ 56);
      r1 = base + ((k1 < 6 ? k1 + 6 : k1 - 6) << 6) + ((v1 & 63) ^ 56);
      r2 = base + ((k2 < 6 ? k2 + 6 : k2 - 6) << 6) + ((v2 & 63) ^ 56);
      r3 = base + ((k3 < 6 ? k3 + 6 : k3 - 6) << 6) + ((v3 & 63) ^ 56);
    } else {
      r0 = base + v0; r1 = base + v1; r2 = base + v2; r3 = base + v3;
    }
    const uint2 x0 = mb[(size_t)r0 << 6];
    const uint2 x1 = mb[(size_t)r1 << 6];
    const uint2 x2 = mb[(size_t)r2 << 6];
    const uint2 x3 = mb[(size_t)r3 << 6];
    bf4_acc(x0, a0); bf4_acc(x1, a1); bf4_acc(x2, a0); bf4_acc(x3, a1);
  }
  for (; i < len; ++i) {
    const int v = vals[i];
    unsigned r;
    if (WAITER) {
      const int k = v >> 6;
      r = base + ((k < 6 ? k + 6 : k - 6) << 6) + ((v & 63) ^ 56);
    } else {
      r = base + v;
    }
    bf4_acc(mb[(size_t)r << 6], a0);
  }

  float4 o;
  o.x = fminf(fmaxf(a0.x + a1.x, 0.f), 1.f);
  o.y = fminf(fmaxf(a0.y + a1.y, 0.f), 1.f);
  o.z = fminf(fmaxf(a0.z + a1.z, 0.f), 1.f);
  o.w = fminf(fmaxf(a0.w + a1.w, 0.f), 1.f);
  float4* ob = reinterpret_cast<float4*>(out) +
               (WAITER ? (size_t)n_bags * 64 : 0);
  ob[(size_t)bag * 64 + lane] = o;
}

__global__ __launch_bounds__(256) void gather_kernel(
    const uint2* __restrict__ merged, const int* __restrict__ values,
    const int* __restrict__ lengths, const int* __restrict__ kings,
    const int* __restrict__ offs, const int* __restrict__ perm_m,
    const int* __restrict__ perm_w, float* __restrict__ out, int n_bags,
    int chunk, int half_blocks) {
  const int b = blockIdx.x;
  if (b < half_blocks) {
    gather_body<false>(merged, values, lengths, kings, offs, perm_m, out,
                       n_bags, chunk, b);
  } else {
    gather_body<true>(merged, values, lengths, kings, offs, perm_w, out,
                      n_bags, chunk, b - half_blocks);
  }
}

extern "C" void kernel_launch(void* const* d_in, const int* in_sizes, int n_in,
                              void* d_out, int out_size, void* d_ws, size_t ws_size,
                              hipStream_t stream) {
  const float* pieces = (const float*)d_in[0];
  const float* ranks  = (const float*)d_in[1];
  const float* files  = (const float*)d_in[2];
  const float* tiles  = (const float*)d_in[3];
  const float* mask   = (const float*)d_in[4];
  const int*   values = (const int*)d_in[5];
  const int*   lengths= (const int*)d_in[6];
  const int*   kings  = (const int*)d_in[7];
  float* out = (float*)d_out;

  const int B = in_sizes[6];  // number of bags

  // workspace layout (256B aligned)
  const size_t bN = ((size_t)B * 4 + 255) & ~(size_t)255;
  int* offs   = (int*)d_ws;
  int* perm_m = (int*)((char*)d_ws + bN);
  int* perm_w = (int*)((char*)d_ws + 2 * bN);
  uint2* merged = (uint2*)((char*)d_ws + 3 * bN);  // bf16 table, 25.2 MB

  prep_kernel<<<MAT_BLOCKS + 3, 256, 0, stream>>>(
      tiles, pieces, ranks, files, mask, merged, lengths, kings,
      offs, perm_m, perm_w, B);

  const int chunk = (B + 7) / 8;                 // bags per XCD chunk
  const int half_blocks = 8 * ((chunk + 3) / 4); // blocks per view
  gather_kernel<<<2 * half_blocks, 256, 0, stream>>>(
      merged, values, lengths, kings, offs, perm_m, perm_w, out, B,
      chunk, half_blocks);
}

// Round 6
// 183.219 us; speedup vs baseline: 1.5578x; 1.0800x over previous
//
#include <hip/hip_runtime.h>

#define DOUT 256
#define NROWS 49152              // 64 king squares * 12 planes * 64 squares
#define MATB (NROWS / 16)        // 3072 materialize blocks of 1024 threads

__device__ __forceinline__ float4 ld4(const float* p) {
  return *reinterpret_cast<const float4*>(p);
}

// round-to-nearest-even f32 -> bf16, packed pair (a in low16, b in high16)
__device__ __forceinline__ unsigned rne2(float a, float b) {
  unsigned ua = __float_as_uint(a), ub = __float_as_uint(b);
  ua += 0x7FFFu + ((ua >> 16) & 1u);
  ub += 0x7FFFu + ((ub >> 16) & 1u);
  return (ua >> 16) | (ub & 0xFFFF0000u);
}

// accumulate 4 bf16 (packed in uint2) into float4
__device__ __forceinline__ void bf4_acc(uint2 w, float4& acc) {
  acc.x += __uint_as_float(w.x << 16);
  acc.y += __uint_as_float(w.x & 0xFFFF0000u);
  acc.z += __uint_as_float(w.y << 16);
  acc.w += __uint_as_float(w.y & 0xFFFF0000u);
}

// prep: block 0 = index work (scan + dual counting sort, 16 waves, overlaps
// the materialize blocks); blocks 1..MATB = bf16 table materialize.
__global__ __launch_bounds__(1024) void prep_kernel(
    const float* __restrict__ tiles, const float* __restrict__ pieces,
    const float* __restrict__ ranks, const float* __restrict__ files,
    const float* __restrict__ mask, uint2* __restrict__ merged,
    const int* __restrict__ lengths, const int* __restrict__ kings,
    int* __restrict__ offs, int* __restrict__ perm_m, int* __restrict__ perm_w,
    int n_bags) {
  const int bid = blockIdx.x;
  const int t = threadIdx.x;
  if (bid == 0) {
    __shared__ int part[1024];
    __shared__ int histM[64], histW[64], curW[64];
    const int nb = n_bags;
    // ---- exclusive scan of lengths: thread t owns [t*16, t*16+16) ----
    int v[16];
    const int base = t * 16;
    int s = 0;
    if (base + 16 <= nb) {
#pragma unroll
      for (int j = 0; j < 16; j += 4) {
        const int4 x = *reinterpret_cast<const int4*>(lengths + base + j);
        v[j] = x.x; v[j + 1] = x.y; v[j + 2] = x.z; v[j + 3] = x.w;
      }
#pragma unroll
      for (int j = 0; j < 16; ++j) s += v[j];
    } else {
      for (int j = 0; j < 16; ++j) {
        const int idx = base + j;
        v[j] = (idx < nb) ? lengths[idx] : 0;
        s += v[j];
      }
    }
    part[t] = s;
    __syncthreads();
    for (int off = 1; off < 1024; off <<= 1) {
      const int w = (t >= off) ? part[t - off] : 0;
      __syncthreads();
      part[t] += w;
      __syncthreads();
    }
    int run = part[t] - s;
    for (int j = 0; j < 16; ++j) {
      const int idx = base + j;
      if (idx < nb) { offs[idx] = run; run += v[j]; }
    }
    // ---- dual histogram over king columns (int2-coalesced) ----
    if (t < 64) { histM[t] = 0; histW[t] = 0; }
    __syncthreads();
    for (int i = t; i < nb; i += 1024) {
      const int2 kk = *reinterpret_cast<const int2*>(kings + 2 * i);
      atomicAdd(&histM[kk.x], 1);
      atomicAdd(&histW[kk.y], 1);
    }
    __syncthreads();
    // ---- bucket starts (reuse histM as mover cursor, curW as waiter) ----
    if (t == 0) {
      int r = 0;
      for (int k = 0; k < 64; ++k) { const int h = histM[k]; histM[k] = r; r += h; }
    }
    if (t == 1) {
      int r = 0;
      for (int k = 0; k < 64; ++k) { curW[k] = r; r += histW[k]; }
    }
    __syncthreads();
    // ---- scatter both permutations ----
    for (int i = t; i < nb; i += 1024) {
      const int2 kk = *reinterpret_cast<const int2*>(kings + 2 * i);
      const int pm = atomicAdd(&histM[kk.x], 1);
      perm_m[pm] = i;
      const int pw = atomicAdd(&curW[kk.y], 1);
      perm_w[pw] = i;
    }
    return;
  }
  // ---- materialize: 16 rows per block, float4 loads, bf16 packed store ----
  const int row = ((bid - 1) << 4) + (t >> 6);
  const int lane = t & 63;
  const int p = row & 63;
  const int sk = row >> 6;
  const int r = p >> 3, f = p & 7;
  const float m = mask[row];
  const int d0 = lane << 2;
  const float4 tl = ld4(tiles + (size_t)row * DOUT + d0);
  const float4 pc = ld4(pieces + (size_t)sk * DOUT + d0);
  const float4 rk = ld4(ranks + (size_t)(sk * 8 + r) * DOUT + d0);
  const float4 fl = ld4(files + (size_t)(sk * 8 + f) * DOUT + d0);
  float4 o;
  o.x = fmaf(pc.x + rk.x + fl.x, m, tl.x);
  o.y = fmaf(pc.y + rk.y + fl.y, m, tl.y);
  o.z = fmaf(pc.z + rk.z + fl.z, m, tl.z);
  o.w = fmaf(pc.w + rk.w + fl.w, m, tl.w);
  uint2 w;
  w.x = rne2(o.x, o.y);
  w.y = rne2(o.z, o.w);
  merged[(size_t)row * 64 + lane] = w;
}

// gather: one wave per bag over the bf16 table; bags sorted by king so each
// XCD (bid%8) walks a contiguous king range -> slice (393 KB) L2-resident.
// First half of blocks: mover view (a). Second half: waiter/flipped view (b).
// NOTE: accumulation order is frozen (absmax margin) — do not reorder.
template <bool WAITER>
__device__ __forceinline__ void gather_body(
    const uint2* __restrict__ merged, const int* __restrict__ values,
    const int* __restrict__ lengths, const int* __restrict__ kings,
    const int* __restrict__ offs, const int* __restrict__ perm,
    float* __restrict__ out, int n_bags, int chunk, int b) {
  const int c = b & 7;          // XCD id under bid%8 round-robin
  const int j = b >> 3;         // sequence within this XCD's chunk
  const int pos = c * chunk + (j << 2) + (threadIdx.x >> 6);
  const int lim = min((c + 1) * chunk, n_bags);
  if (pos >= lim) return;
  const int lane = threadIdx.x & 63;
  const int bag = perm[pos];
  const int len = lengths[bag];
  const int kg = kings[2 * bag + (WAITER ? 1 : 0)];
  const int base = (WAITER ? (((7 - (kg >> 3)) << 3) + (kg & 7)) : kg) * 768;
  const int* __restrict__ vals = values + offs[bag];
  const uint2* __restrict__ mb = merged + lane;  // lane covers dims 4l..4l+3

  float4 a0 = {0.f, 0.f, 0.f, 0.f}, a1 = {0.f, 0.f, 0.f, 0.f};

  int i = 0;
  for (; i + 4 <= len; i += 4) {
    const int v0 = vals[i], v1 = vals[i + 1], v2 = vals[i + 2], v3 = vals[i + 3];
    unsigned r0, r1, r2, r3;
    if (WAITER) {
      const int k0 = v0 >> 6, k1 = v1 >> 6, k2 = v2 >> 6, k3 = v3 >> 6;
      r0 = base + ((k0 < 6 ? k0 + 6 : k0 - 6) << 6) + ((v0 & 63) ^ 56);
      r1 = base + ((k1 < 6 ? k1 + 6 : k1 - 6) << 6) + ((v1 & 63) ^ 56);
      r2 = base + ((k2 < 6 ? k2 + 6 : k2 - 6) << 6) + ((v2 & 63) ^ 56);
      r3 = base + ((k3 < 6 ? k3 + 6 : k3 - 6) << 6) + ((v3 & 63) ^ 56);
    } else {
      r0 = base + v0; r1 = base + v1; r2 = base + v2; r3 = base + v3;
    }
    const uint2 x0 = mb[(size_t)r0 << 6];
    const uint2 x1 = mb[(size_t)r1 << 6];
    const uint2 x2 = mb[(size_t)r2 << 6];
    const uint2 x3 = mb[(size_t)r3 << 6];
    bf4_acc(x0, a0); bf4_acc(x1, a1); bf4_acc(x2, a0); bf4_acc(x3, a1);
  }
  for (; i < len; ++i) {
    const int v = vals[i];
    unsigned r;
    if (WAITER) {
      const int k = v >> 6;
      r = base + ((k < 6 ? k + 6 : k - 6) << 6) + ((v & 63) ^ 56);
    } else {
      r = base + v;
    }
    bf4_acc(mb[(size_t)r << 6], a0);
  }

  float4 o;
  o.x = fminf(fmaxf(a0.x + a1.x, 0.f), 1.f);
  o.y = fminf(fmaxf(a0.y + a1.y, 0.f), 1.f);
  o.z = fminf(fmaxf(a0.z + a1.z, 0.f), 1.f);
  o.w = fminf(fmaxf(a0.w + a1.w, 0.f), 1.f);
  float4* ob = reinterpret_cast<float4*>(out) +
               (WAITER ? (size_t)n_bags * 64 : 0);
  ob[(size_t)bag * 64 + lane] = o;
}

__global__ __launch_bounds__(256) void gather_kernel(
    const uint2* __restrict__ merged, const int* __restrict__ values,
    const int* __restrict__ lengths, const int* __restrict__ kings,
    const int* __restrict__ offs, const int* __restrict__ perm_m,
    const int* __restrict__ perm_w, float* __restrict__ out, int n_bags,
    int chunk, int half_blocks) {
  const int b = blockIdx.x;
  if (b < half_blocks) {
    gather_body<false>(merged, values, lengths, kings, offs, perm_m, out,
                       n_bags, chunk, b);
  } else {
    gather_body<true>(merged, values, lengths, kings, offs, perm_w, out,
                      n_bags, chunk, b - half_blocks);
  }
}

extern "C" void kernel_launch(void* const* d_in, const int* in_sizes, int n_in,
                              void* d_out, int out_size, void* d_ws, size_t ws_size,
                              hipStream_t stream) {
  const float* pieces = (const float*)d_in[0];
  const float* ranks  = (const float*)d_in[1];
  const float* files  = (const float*)d_in[2];
  const float* tiles  = (const float*)d_in[3];
  const float* mask   = (const float*)d_in[4];
  const int*   values = (const int*)d_in[5];
  const int*   lengths= (const int*)d_in[6];
  const int*   kings  = (const int*)d_in[7];
  float* out = (float*)d_out;

  const int B = in_sizes[6];  // number of bags

  // workspace layout (256B aligned)
  const size_t bN = ((size_t)B * 4 + 255) & ~(size_t)255;
  int* offs   = (int*)d_ws;
  int* perm_m = (int*)((char*)d_ws + bN);
  int* perm_w = (int*)((char*)d_ws + 2 * bN);
  uint2* merged = (uint2*)((char*)d_ws + 3 * bN);  // bf16 table, 25.2 MB

  prep_kernel<<<MATB + 1, 1024, 0, stream>>>(
      tiles, pieces, ranks, files, mask, merged, lengths, kings,
      offs, perm_m, perm_w, B);

  const int chunk = (B + 7) / 8;                 // bags per XCD chunk
  const int half_blocks = 8 * ((chunk + 3) / 4); // blocks per view
  gather_kernel<<<2 * half_blocks, 256, 0, stream>>>(
      merged, values, lengths, kings, offs, perm_m, perm_w, out, B,
      chunk, half_blocks);
}

// Round 9
// 182.521 us; speedup vs baseline: 1.5637x; 1.0038x over previous
//
#include <hip/hip_runtime.h>

#define DOUT 256
#define NROWS 49152              // 64 king squares * 12 planes * 64 squares
#define MATB (NROWS / 16)        // 3072 materialize blocks of 1024 threads

__device__ __forceinline__ float4 ld4(const float* p) {
  return *reinterpret_cast<const float4*>(p);
}

// round-to-nearest-even f32 -> bf16, packed pair (a in low16, b in high16)
__device__ __forceinline__ unsigned rne2(float a, float b) {
  unsigned ua = __float_as_uint(a), ub = __float_as_uint(b);
  ua += 0x7FFFu + ((ua >> 16) & 1u);
  ub += 0x7FFFu + ((ub >> 16) & 1u);
  return (ua >> 16) | (ub & 0xFFFF0000u);
}

// accumulate 4 bf16 (packed in uint2) into float4
__device__ __forceinline__ void bf4_acc(uint2 w, float4& acc) {
  acc.x += __uint_as_float(w.x << 16);
  acc.y += __uint_as_float(w.x & 0xFFFF0000u);
  acc.z += __uint_as_float(w.y << 16);
  acc.w += __uint_as_float(w.y & 0xFFFF0000u);
}

// prep: block 0 = index work (shuffle-scan + dual per-wave counting sort,
// overlaps materialize blocks); blocks 1..MATB = bf16 table materialize.
__global__ __launch_bounds__(1024) void prep_kernel(
    const float* __restrict__ tiles, const float* __restrict__ pieces,
    const float* __restrict__ ranks, const float* __restrict__ files,
    const float* __restrict__ mask, uint2* __restrict__ merged,
    const int* __restrict__ lengths, const int* __restrict__ kings,
    int* __restrict__ offs, int* __restrict__ perm_m, int* __restrict__ perm_w,
    int n_bags) {
  const int bid = blockIdx.x;
  const int t = threadIdx.x;
  if (bid == 0) {
    __shared__ int wsum[16];
    __shared__ int histM[16][64];
    __shared__ int histW[16][64];
    const int nb = n_bags;
    const int lane = t & 63;
    const int wid = t >> 6;
    // ---- zero hists (2048 ints / 1024 threads) ----
    ((int*)histM)[t] = 0;
    ((int*)histW)[t] = 0;
    // ---- exclusive scan of lengths: thread t owns [t*16, t*16+16) ----
    int v[16];
    const int base = t * 16;
    int s = 0;
    if (base + 16 <= nb) {
#pragma unroll
      for (int j = 0; j < 16; j += 4) {
        const int4 x = *reinterpret_cast<const int4*>(lengths + base + j);
        v[j] = x.x; v[j + 1] = x.y; v[j + 2] = x.z; v[j + 3] = x.w;
      }
#pragma unroll
      for (int j = 0; j < 16; ++j) s += v[j];
    } else {
      for (int j = 0; j < 16; ++j) {
        const int idx = base + j;
        v[j] = (idx < nb) ? lengths[idx] : 0;
        s += v[j];
      }
    }
    // wave-level inclusive scan via shuffles (no barriers)
    int inc = s;
#pragma unroll
    for (int d = 1; d < 64; d <<= 1) {
      const int y = __shfl_up(inc, d, 64);
      if (lane >= d) inc += y;
    }
    if (lane == 63) wsum[wid] = inc;
    __syncthreads();
    if (wid == 0) {
      int wv = (lane < 16) ? wsum[lane] : 0;
#pragma unroll
      for (int d = 1; d < 16; d <<= 1) {
        const int y = __shfl_up(wv, d, 64);
        if (lane >= d) wv += y;
      }
      if (lane < 16) wsum[lane] = wv;  // inclusive wave totals
    }
    __syncthreads();
    {
      const int waveBase = wid ? wsum[wid - 1] : 0;
      int run = waveBase + inc - s;  // exclusive prefix for this thread
      for (int j = 0; j < 16; ++j) {
        const int idx = base + j;
        if (idx < nb) { offs[idx] = run; run += v[j]; }
      }
    }
    // ---- per-wave dual histogram (no cross-wave contention) ----
    for (int i = t; i < nb; i += 1024) {
      const int2 kk = *reinterpret_cast<const int2*>(kings + 2 * i);
      atomicAdd(&histM[wid][kk.x], 1);
      atomicAdd(&histW[wid][kk.y], 1);
    }
    __syncthreads();
    // ---- bucket starts + per-wave cursor bases (wave0: M, wave1: W) ----
    if (wid < 2) {
      int (*h)[64] = wid ? histW : histM;
      const int k = lane;
      int sum = 0;
#pragma unroll
      for (int w = 0; w < 16; ++w) sum += h[w][k];
      int incl = sum;
#pragma unroll
      for (int d = 1; d < 64; d <<= 1) {
        const int y = __shfl_up(incl, d, 64);
        if (k >= d) incl += y;
      }
      int run = incl - sum;  // global bucket start
#pragma unroll
      for (int w = 0; w < 16; ++w) { const int c = h[w][k]; h[w][k] = run; run += c; }
    }
    __syncthreads();
    // ---- scatter both permutations via per-wave cursors ----
    for (int i = t; i < nb; i += 1024) {
      const int2 kk = *reinterpret_cast<const int2*>(kings + 2 * i);
      const int pm = atomicAdd(&histM[wid][kk.x], 1);
      perm_m[pm] = i;
      const int pw = atomicAdd(&histW[wid][kk.y], 1);
      perm_w[pw] = i;
    }
    return;
  }
  // ---- materialize: 16 rows per block, float4 loads, bf16 packed store ----
  const int row = ((bid - 1) << 4) + (t >> 6);
  const int lane = t & 63;
  const int p = row & 63;
  const int sk = row >> 6;
  const int r = p >> 3, f = p & 7;
  const float m = mask[row];
  const int d0 = lane << 2;
  const float4 tl = ld4(tiles + (size_t)row * DOUT + d0);
  const float4 pc = ld4(pieces + (size_t)sk * DOUT + d0);
  const float4 rk = ld4(ranks + (size_t)(sk * 8 + r) * DOUT + d0);
  const float4 fl = ld4(files + (size_t)(sk * 8 + f) * DOUT + d0);
  float4 o;
  o.x = fmaf(pc.x + rk.x + fl.x, m, tl.x);
  o.y = fmaf(pc.y + rk.y + fl.y, m, tl.y);
  o.z = fmaf(pc.z + rk.z + fl.z, m, tl.z);
  o.w = fmaf(pc.w + rk.w + fl.w, m, tl.w);
  uint2 w;
  w.x = rne2(o.x, o.y);
  w.y = rne2(o.z, o.w);
  merged[(size_t)row * 64 + lane] = w;
}

// gather: one wave per bag over the bf16 table; bags sorted by king so each
// XCD (bid%8) walks a contiguous king range -> slice (393 KB) L2-resident.
// First half of blocks: mover view (a). Second half: waiter/flipped view (b).
// NOTE: accumulation order is FROZEN bit-exact (absmax margin 2.4%): the
// 8-unroll adds into a0/a1 in exactly the order of two 4-unroll iterations.
template <bool WAITER>
__device__ __forceinline__ void gather_body(
    const uint2* __restrict__ merged, const int* __restrict__ values,
    const int* __restrict__ lengths, const int* __restrict__ kings,
    const int* __restrict__ offs, const int* __restrict__ perm,
    float* __restrict__ out, int n_bags, int chunk, int b) {
  const int c = b & 7;          // XCD id under bid%8 round-robin
  const int j = b >> 3;         // sequence within this XCD's chunk
  const int pos = c * chunk + (j << 2) + (threadIdx.x >> 6);
  const int lim = min((c + 1) * chunk, n_bags);
  if (pos >= lim) return;
  const int lane = threadIdx.x & 63;
  const int bag = perm[pos];
  const int len = lengths[bag];
  const int kg = kings[2 * bag + (WAITER ? 1 : 0)];
  const int base = (WAITER ? (((7 - (kg >> 3)) << 3) + (kg & 7)) : kg) * 768;
  const int* __restrict__ vals = values + offs[bag];
  const uint2* __restrict__ mb = merged + lane;  // lane covers dims 4l..4l+3

  float4 a0 = {0.f, 0.f, 0.f, 0.f}, a1 = {0.f, 0.f, 0.f, 0.f};

  int i = 0;
  for (; i + 8 <= len; i += 8) {
    const int v0 = vals[i],     v1 = vals[i + 1], v2 = vals[i + 2], v3 = vals[i + 3];
    const int v4 = vals[i + 4], v5 = vals[i + 5], v6 = vals[i + 6], v7 = vals[i + 7];
    unsigned r0, r1, r2, r3, r4, r5, r6, r7;
    if (WAITER) {
      const int k0 = v0 >> 6, k1 = v1 >> 6, k2 = v2 >> 6, k3 = v3 >> 6;
      const int k4 = v4 >> 6, k5 = v5 >> 6, k6 = v6 >> 6, k7 = v7 >> 6;
      r0 = base + ((k0 < 6 ? k0 + 6 : k0 - 6) << 6) + ((v0 & 63) ^ 56);
      r1 = base + ((k1 < 6 ? k1 + 6 : k1 - 6) << 6) + ((v1 & 63) ^ 56);
      r2 = base + ((k2 < 6 ? k2 + 6 : k2 - 6) << 6) + ((v2 & 63) ^ 56);
      r3 = base + ((k3 < 6 ? k3 + 6 : k3 - 6) << 6) + ((v3 & 63) ^ 56);
      r4 = base + ((k4 < 6 ? k4 + 6 : k4 - 6) << 6) + ((v4 & 63) ^ 56);
      r5 = base + ((k5 < 6 ? k5 + 6 : k5 - 6) << 6) + ((v5 & 63) ^ 56);
      r6 = base + ((k6 < 6 ? k6 + 6 : k6 - 6) << 6) + ((v6 & 63) ^ 56);
      r7 = base + ((k7 < 6 ? k7 + 6 : k7 - 6) << 6) + ((v7 & 63) ^ 56);
    } else {
      r0 = base + v0; r1 = base + v1; r2 = base + v2; r3 = base + v3;
      r4 = base + v4; r5 = base + v5; r6 = base + v6; r7 = base + v7;
    }
    const uint2 x0 = mb[(size_t)r0 << 6];
    const uint2 x1 = mb[(size_t)r1 << 6];
    const uint2 x2 = mb[(size_t)r2 << 6];
    const uint2 x3 = mb[(size_t)r3 << 6];
    const uint2 x4 = mb[(size_t)r4 << 6];
    const uint2 x5 = mb[(size_t)r5 << 6];
    const uint2 x6 = mb[(size_t)r6 << 6];
    const uint2 x7 = mb[(size_t)r7 << 6];
    bf4_acc(x0, a0); bf4_acc(x1, a1); bf4_acc(x2, a0); bf4_acc(x3, a1);
    bf4_acc(x4, a0); bf4_acc(x5, a1); bf4_acc(x6, a0); bf4_acc(x7, a1);
  }
  for (; i + 4 <= len; i += 4) {
    const int v0 = vals[i], v1 = vals[i + 1], v2 = vals[i + 2], v3 = vals[i + 3];
    unsigned r0, r1, r2, r3;
    if (WAITER) {
      const int k0 = v0 >> 6, k1 = v1 >> 6, k2 = v2 >> 6, k3 = v3 >> 6;
      r0 = base + ((k0 < 6 ? k0 + 6 : k0 - 6) << 6) + ((v0 & 63) ^ 56);
      r1 = base + ((k1 < 6 ? k1 + 6 : k1 - 6) << 6) + ((v1 & 63) ^ 56);
      r2 = base + ((k2 < 6 ? k2 + 6 : k2 - 6) << 6) + ((v2 & 63) ^ 56);
      r3 = base + ((k3 < 6 ? k3 + 6 : k3 - 6) << 6) + ((v3 & 63) ^ 56);
    } else {
      r0 = base + v0; r1 = base + v1; r2 = base + v2; r3 = base + v3;
    }
    const uint2 x0 = mb[(size_t)r0 << 6];
    const uint2 x1 = mb[(size_t)r1 << 6];
    const uint2 x2 = mb[(size_t)r2 << 6];
    const uint2 x3 = mb[(size_t)r3 << 6];
    bf4_acc(x0, a0); bf4_acc(x1, a1); bf4_acc(x2, a0); bf4_acc(x3, a1);
  }
  for (; i < len; ++i) {
    const int v = vals[i];
    unsigned r;
    if (WAITER) {
      const int k = v >> 6;
      r = base + ((k < 6 ? k + 6 : k - 6) << 6) + ((v & 63) ^ 56);
    } else {
      r = base + v;
    }
    bf4_acc(mb[(size_t)r << 6], a0);
  }

  float4 o;
  o.x = fminf(fmaxf(a0.x + a1.x, 0.f), 1.f);
  o.y = fminf(fmaxf(a0.y + a1.y, 0.f), 1.f);
  o.z = fminf(fmaxf(a0.z + a1.z, 0.f), 1.f);
  o.w = fminf(fmaxf(a0.w + a1.w, 0.f), 1.f);
  float4* ob = reinterpret_cast<float4*>(out) +
               (WAITER ? (size_t)n_bags * 64 : 0);
  ob[(size_t)bag * 64 + lane] = o;
}

__global__ __launch_bounds__(256) void gather_kernel(
    const uint2* __restrict__ merged, const int* __restrict__ values,
    const int* __restrict__ lengths, const int* __restrict__ kings,
    const int* __restrict__ offs, const int* __restrict__ perm_m,
    const int* __restrict__ perm_w, float* __restrict__ out, int n_bags,
    int chunk, int half_blocks) {
  const int b = blockIdx.x;
  if (b < half_blocks) {
    gather_body<false>(merged, values, lengths, kings, offs, perm_m, out,
                       n_bags, chunk, b);
  } else {
    gather_body<true>(merged, values, lengths, kings, offs, perm_w, out,
                      n_bags, chunk, b - half_blocks);
  }
}

extern "C" void kernel_launch(void* const* d_in, const int* in_sizes, int n_in,
                              void* d_out, int out_size, void* d_ws, size_t ws_size,
                              hipStream_t stream) {
  const float* pieces = (const float*)d_in[0];
  const float* ranks  = (const float*)d_in[1];
  const float* files  = (const float*)d_in[2];
  const float* tiles  = (const float*)d_in[3];
  const float* mask   = (const float*)d_in[4];
  const int*   values = (const int*)d_in[5];
  const int*   lengths= (const int*)d_in[6];
  const int*   kings  = (const int*)d_in[7];
  float* out = (float*)d_out;

  const int B = in_sizes[6];  // number of bags

  // workspace layout (256B aligned)
  const size_t bN = ((size_t)B * 4 + 255) & ~(size_t)255;
  int* offs   = (int*)d_ws;
  int* perm_m = (int*)((char*)d_ws + bN);
  int* perm_w = (int*)((char*)d_ws + 2 * bN);
  uint2* merged = (uint2*)((char*)d_ws + 3 * bN);  // bf16 table, 25.2 MB

  prep_kernel<<<MATB + 1, 1024, 0, stream>>>(
      tiles, pieces, ranks, files, mask, merged, lengths, kings,
      offs, perm_m, perm_w, B);

  const int chunk = (B + 7) / 8;                 // bags per XCD chunk
  const int half_blocks = 8 * ((chunk + 3) / 4); // blocks per view
  gather_kernel<<<2 * half_blocks, 256, 0, stream>>>(
      merged, values, lengths, kings, offs, perm_m, perm_w, out, B,
      chunk, half_blocks);
}